// Round 11
// baseline (170.998 us; speedup 1.0000x reference)
//
#include <hip/hip_runtime.h>

// Sizes (fixed by the problem)
#define B_ 8192
#define T_ 256
#define I_ 28
#define H_ 10

// d_out layout: [B*T*H] output, then [2*B*H] h_final
#define OUT_MAIN (B_ * T_ * H_)   // 20971520
#define BH (B_ * H_)              // 81920

typedef __bf16 bf16x8 __attribute__((ext_vector_type(8)));
typedef float f32x16 __attribute__((ext_vector_type(16)));
typedef float f32x4  __attribute__((ext_vector_type(4)));
typedef float f32x2  __attribute__((ext_vector_type(2)));
union W4u { unsigned int w[4]; bf16x8 v; };

__device__ __forceinline__ float fast_tanh(float x) {
    float e = __builtin_amdgcn_exp2f(x * 2.885390081777927f);
    return __builtin_fmaf(-2.0f, __builtin_amdgcn_rcpf(e + 1.0f), 1.0f);
}

__device__ __forceinline__ unsigned short f2bf(float f) {  // f32 -> bf16 RNE
    unsigned u = __float_as_uint(f);
    unsigned r = ((u >> 16) & 1) + 0x7fff;
    return (unsigned short)((u + r) >> 16);
}

// pack (f0,f1) -> bf16 pair dh, and residual pair dl (split-bf16: f ~= hi + lo)
__device__ __forceinline__ void cvtpair(float f0, float f1, unsigned& dh, unsigned& dl) {
    asm("v_cvt_pk_bf16_f32 %0, %1, %2" : "=v"(dh) : "v"(f0), "v"(f1));
    float r0 = f0 - __uint_as_float(dh << 16);
    float r1 = f1 - __uint_as_float(dh & 0xffff0000u);
    asm("v_cvt_pk_bf16_f32 %0, %1, %2" : "=v"(dl) : "v"(r0), "v"(r1));
}

// C->B rebuild (validated r7): pads land exactly 0
#define REBUILD(vv0,vv1,vv2,vv3,vv4,vv5, DST) { \
    unsigned t01, t23, t45, w3 = 0; \
    asm("v_cvt_pk_bf16_f32 %0, %1, %2" : "=v"(t01) : "v"(vv0), "v"(vv1)); \
    asm("v_cvt_pk_bf16_f32 %0, %1, %2" : "=v"(t23) : "v"(vv2), "v"(vv3)); \
    asm("v_cvt_pk_bf16_f32 %0, %1, %2" : "=v"(t45) : "v"(vv4), "v"(vv5)); \
    asm volatile("s_nop 1" : "+v"(t01), "+v"(t23), "+v"(t45)); \
    asm("v_permlane32_swap_b32 %0, %1" : "+v"(t01), "+v"(t45)); \
    asm("v_permlane32_swap_b32 %0, %1" : "+v"(t23), "+v"(w3)); \
    W4u nb_; nb_.w[0]=t01; nb_.w[1]=t23; nb_.w[2]=t45; nb_.w[3]=w3; \
    DST = nb_.v; }

// ---- r11 memory machinery: coalesced fill of an LDS x-stage ------------
// Stage layout: [batch 0..31][float4 slot 0..55] padded to 57 (slot 56 = pad,
// zeroed once). Batch block = x[b][t0..t0+7][:] = 896 B CONTIGUOUS in x ->
// fill is 28 coalesced 64-lane dwordx4 loads (~15 lines each vs 64 scattered).
// Rolling ring L0..L6; vmcnt(8) = 6 younger loads + >=2 younger stores (stores
// are volatile asm -> deterministic count). Fill-block lookahead crosses the
// 8-step block boundary (rounds 21..27 load for block k+2, base XFb, clamped).
#define GLD4(dst, addr) \
    asm volatile("global_load_dwordx4 %0, %1, off" : "=v"(dst) : "v"(addr));
#define WAITL(L, N) asm volatile("s_waitcnt vmcnt(" #N ")" : "+v"(L));
#define GST4(addr, val) \
    asm volatile("global_store_dwordx4 %0, %1, off" :: "v"(addr), "v"(val));
#define GST2(addr, val) \
    asm volatile("global_store_dwordx2 %0, %1, off" :: "v"(addr), "v"(val));

// per-lane offsets for fill round r (r compile-time): q = r*64+lane float4s;
// b = q/56 (exact magic: (q>>3)*9363>>16 == (q>>3)/7 for q>>3 < 91k), rem = q%56
#define PLOFF(r) ({ int q_ = 64*(r) + l; int b_ = ((q_>>3)*9363)>>16; \
                    int rm_ = q_ - 56*b_; b_*7168 + rm_*4; })       /* floats in x */
#define PDOFF(r) ({ int q_ = 64*(r) + l; int b_ = ((q_>>3)*9363)>>16; \
                    int rm_ = q_ - 56*b_; b_*57 + rm_; })           /* f32x4 in stage */

#define FILLR(r, L) { \
    WAITL(L, 8) \
    stage[fb][PDOFF(r)] = L; \
    const float* s_ = ((r) < 21) ? (XFa + PLOFF((r)+7)) : (XFb + PLOFF((r)-21)); \
    GLD4(L, s_) }

#define PFILLR(r, L) { \
    WAITL(L, 6) \
    stage[0][PDOFF(r)] = L; \
    const float* s_ = ((r) < 21) ? (XP0 + PLOFF((r)+7)) : (XP1 + PLOFF((r)-21)); \
    GLD4(L, s_) }

// per-step x fragments from LDS: SA=k[8h..8h+3] SB=k[8h+4..8h+7]
// SC=k[16+8h..19+8h] SD=k[20+8h..23+8h] (h=1: SD spans next row / zeroed pad --
// multiplied by zero weights, finite, harmless)
#define SREAD(bi, trel) { \
    int ix_ = n*57 + (trel)*7 + 2*h; \
    SA = stage[bi][ix_];   SB = stage[bi][ix_+1]; \
    SC = stage[bi][ix_+4]; SD = stage[bi][ix_+5]; }

// XC = b0 + Wh*xl + Wl*xh + Wh*xh, three independent 2-MFMA chains (r10)
#define MAKEXC() { \
    W4u xhA, xlA, xhB, xlB; \
    cvtpair(SA[0], SA[1], xhA.w[0], xlA.w[0]); \
    cvtpair(SA[2], SA[3], xhA.w[1], xlA.w[1]); \
    cvtpair(SB[0], SB[1], xhA.w[2], xlA.w[2]); \
    cvtpair(SB[2], SB[3], xhA.w[3], xlA.w[3]); \
    cvtpair(SC[0], SC[1], xhB.w[0], xlB.w[0]); \
    cvtpair(SC[2], SC[3], xhB.w[1], xlB.w[1]); \
    cvtpair(SD[0], SD[1], xhB.w[2], xlB.w[2]); \
    cvtpair(SD[2], SD[3], xhB.w[3], xlB.w[3]); \
    f32x16 xcA = __builtin_amdgcn_mfma_f32_32x32x16_bf16(Axh0, xlA.v, C0SEED, 0,0,0); \
    f32x16 xcB = __builtin_amdgcn_mfma_f32_32x32x16_bf16(Axl0, xhA.v, ZERO16, 0,0,0); \
    f32x16 xcC = __builtin_amdgcn_mfma_f32_32x32x16_bf16(Axh0, xhA.v, ZERO16, 0,0,0); \
    xcA = __builtin_amdgcn_mfma_f32_32x32x16_bf16(Axh1, xlB.v, xcA, 0,0,0); \
    xcB = __builtin_amdgcn_mfma_f32_32x32x16_bf16(Axl1, xhB.v, xcB, 0,0,0); \
    xcC = __builtin_amdgcn_mfma_f32_32x32x16_bf16(Axh1, xhB.v, xcC, 0,0,0); \
    XC[0]=xcA[0]+xcB[0]+xcC[0]; XC[1]=xcA[1]+xcB[1]+xcC[1]; \
    XC[2]=xcA[2]+xcB[2]+xcC[2]; XC[3]=xcA[3]+xcB[3]+xcC[3]; \
    XC[4]=xcA[4]+xcB[4]+xcC[4]; XC[5]=xcA[5]+xcB[5]+xcC[5]; }

#define STEPCOMMON(t) \
    f32x16 c1a = __builtin_amdgcn_mfma_f32_32x32x16_bf16(Ahh1, Bh1, C1SEED, 0,0,0); \
    f32x16 c0  = __builtin_amdgcn_mfma_f32_32x32x16_bf16(Ahh0, Bh0, XC, 0,0,0); \
    v0 = fast_tanh(c0[0]); v1 = fast_tanh(c0[1]); v2 = fast_tanh(c0[2]); \
    v3 = fast_tanh(c0[3]); v4 = fast_tanh(c0[4]); v5 = fast_tanh(c0[5]); \
    REBUILD(v0,v1,v2,v3,v4,v5, Bh0) \
    f32x16 c1 = __builtin_amdgcn_mfma_f32_32x32x16_bf16(Aih1, Bh0, c1a, 0,0,0);

#define STEPTAIL(t) \
    g0 = fast_tanh(c1[0]); g1 = fast_tanh(c1[1]); g2 = fast_tanh(c1[2]); \
    g3 = fast_tanh(c1[3]); g4 = fast_tanh(c1[4]); g5 = fast_tanh(c1[5]); \
    { f32x4 gv = {g0,g1,g2,g3}; GST4(orow + (t)*H_ + xo, gv) } \
    if (!h) { f32x2 gw = {g4,g5}; GST2(orow + (t)*H_ + 8, gw) } \
    REBUILD(g0,g1,g2,g3,g4,g5, Bh1)

#define STEP(s8, RA,RB,RC,RD) { \
    STEPCOMMON(tb+(s8)) \
    SREAD(cb, (s8)+1) \
    MAKEXC() \
    STEPTAIL(tb+(s8)) \
    FILLR(4*(s8)+0, RA) FILLR(4*(s8)+1, RB) \
    FILLR(4*(s8)+2, RC) FILLR(4*(s8)+3, RD) }

#define STEP7 { \
    STEPCOMMON(tb+7) \
    SREAD(fb, 0) \
    MAKEXC() \
    STEPTAIL(tb+7) }

__global__ __launch_bounds__(64)
__attribute__((amdgpu_waves_per_eu(1, 1)))
void rnn_fused(const float* __restrict__ x, const float* __restrict__ h0in,
               const float* __restrict__ Wih0, const float* __restrict__ Whh0,
               const float* __restrict__ bih0, const float* __restrict__ bhh0,
               const float* __restrict__ Wih1, const float* __restrict__ Whh1,
               const float* __restrict__ bih1, const float* __restrict__ bhh1,
               float* __restrict__ out, float* __restrict__ hfin) {
    const int l = threadIdx.x;
    const int n = l & 31, h = l >> 5;
    const int bb = blockIdx.x * 32;
    const int am = n;

    __shared__ f32x4 stage[2][1824];   // 2 x 32 batches x 57 f32x4 (slot 56 = pad)
    if (l < 32) {                       // zero the pad slots (NaN hygiene for SD h=1)
        f32x4 z = {0.f, 0.f, 0.f, 0.f};
        stage[0][l*57 + 56] = z; stage[1][l*57 + 56] = z;
    }

    // ---- recurrent A-frags (bf16, zero-padded), pinned vs remat (r5 lesson)
    W4u a0u, aiu, ahu;
#pragma unroll
    for (int jj = 0; jj < 4; jj++) {
        int k0 = 8*h + 2*jj, k1 = k0 + 1;
        bool r0 = (am < H_) && (k0 < H_), r1 = (am < H_) && (k1 < H_);
        unsigned lo, hi;
        lo = r0 ? f2bf(Whh0[am*H_+k0]) : 0u; hi = r1 ? f2bf(Whh0[am*H_+k1]) : 0u;
        a0u.w[jj] = lo | (hi<<16);
        lo = r0 ? f2bf(Wih1[am*H_+k0]) : 0u; hi = r1 ? f2bf(Wih1[am*H_+k1]) : 0u;
        aiu.w[jj] = lo | (hi<<16);
        lo = r0 ? f2bf(Whh1[am*H_+k0]) : 0u; hi = r1 ? f2bf(Whh1[am*H_+k1]) : 0u;
        ahu.w[jj] = lo | (hi<<16);
    }
    bf16x8 Ahh0 = a0u.v, Aih1 = aiu.v, Ahh1 = ahu.v;
    asm volatile("" : "+v"(Ahh0), "+v"(Aih1), "+v"(Ahh1));

    // ---- Wih0 split hi/lo A-frags, 2 K-slices
    W4u xh0u, xh1u, xl0u, xl1u;
#pragma unroll
    for (int s = 0; s < 2; s++) {
#pragma unroll
        for (int jj = 0; jj < 4; jj++) {
            int k0 = 16*s + 8*h + 2*jj, k1 = k0 + 1;
            unsigned short h0b=0, h1b=0, l0b=0, l1b=0;
            if (am < H_ && k0 < I_) {
                float f = Wih0[am*I_+k0];
                h0b = f2bf(f);
                l0b = f2bf(f - __uint_as_float(((unsigned)h0b)<<16));
            }
            if (am < H_ && k1 < I_) {
                float f = Wih0[am*I_+k1];
                h1b = f2bf(f);
                l1b = f2bf(f - __uint_as_float(((unsigned)h1b)<<16));
            }
            unsigned wh = (unsigned)h0b | ((unsigned)h1b<<16);
            unsigned wl = (unsigned)l0b | ((unsigned)l1b<<16);
            if (s==0) { xh0u.w[jj]=wh; xl0u.w[jj]=wl; }
            else      { xh1u.w[jj]=wh; xl1u.w[jj]=wl; }
        }
    }
    bf16x8 Axh0 = xh0u.v, Axh1 = xh1u.v, Axl0 = xl0u.v, Axl1 = xl1u.v;
    asm volatile("" : "+v"(Axh0), "+v"(Axh1), "+v"(Axl0), "+v"(Axl1));

    // ---- persistent bias-seeded C tuples + zero seed, pinned
    f32x16 C0SEED, C1SEED, ZERO16;
#pragma unroll
    for (int r = 0; r < 16; r++) { C0SEED[r] = 0.f; C1SEED[r] = 0.f; ZERO16[r] = 0.f; }
#pragma unroll
    for (int r = 0; r < 6; r++) {
        int mm = (r & 3) + 8 * (r >> 2) + 4 * h;
        if (mm < H_) {
            C0SEED[r] = bih0[mm] + bhh0[mm];
            C1SEED[r] = bih1[mm] + bhh1[mm];
        }
    }
    asm volatile("" : "+v"(C0SEED), "+v"(C1SEED), "+v"(ZERO16));

    // ---- initial B fragments from h0 (zero-padded)
    W4u b0u, b1u;
#pragma unroll
    for (int jj = 0; jj < 4; jj++) {
        int k0 = 8*h + 2*jj, k1 = k0 + 1;
        float f0 = (k0 < H_) ? h0in[(bb + n) * H_ + k0] : 0.f;
        float f1 = (k1 < H_) ? h0in[(bb + n) * H_ + k1] : 0.f;
        b0u.w[jj] = (unsigned)f2bf(f0) | ((unsigned)f2bf(f1) << 16);
        f0 = (k0 < H_) ? h0in[BH + (bb + n) * H_ + k0] : 0.f;
        f1 = (k1 < H_) ? h0in[BH + (bb + n) * H_ + k1] : 0.f;
        b1u.w[jj] = (unsigned)f2bf(f0) | ((unsigned)f2bf(f1) << 16);
    }
    bf16x8 Bh0 = b0u.v, Bh1 = b1u.v;

    const float* xf   = x   + (long)bb * (T_ * I_);   // fill base (lane-uniform)
    float*       orow = out + (long)(bb + n) * (T_ * H_);
    const int xo = h ? 4 : 0;

    // ---- prologue: fill stage[0] with x-block 0; prime L0..L6 with block 1
    f32x4 L0, L1, L2, L3, L4, L5, L6, SA, SB, SC, SD;
    const float* XP0 = xf;          // block 0
    const float* XP1 = xf + 224;    // block 1 (896 B)
    GLD4(L0, XP0 + PLOFF(0)) GLD4(L1, XP0 + PLOFF(1)) GLD4(L2, XP0 + PLOFF(2))
    GLD4(L3, XP0 + PLOFF(3)) GLD4(L4, XP0 + PLOFF(4)) GLD4(L5, XP0 + PLOFF(5))
    GLD4(L6, XP0 + PLOFF(6))
    PFILLR(0,L0)  PFILLR(1,L1)  PFILLR(2,L2)  PFILLR(3,L3)
    PFILLR(4,L4)  PFILLR(5,L5)  PFILLR(6,L6)  PFILLR(7,L0)
    PFILLR(8,L1)  PFILLR(9,L2)  PFILLR(10,L3) PFILLR(11,L4)
    PFILLR(12,L5) PFILLR(13,L6) PFILLR(14,L0) PFILLR(15,L1)
    PFILLR(16,L2) PFILLR(17,L3) PFILLR(18,L4) PFILLR(19,L5)
    PFILLR(20,L6) PFILLR(21,L0) PFILLR(22,L1) PFILLR(23,L2)
    PFILLR(24,L3) PFILLR(25,L4) PFILLR(26,L5) PFILLR(27,L6)

    f32x16 XC;
    { SREAD(0, 0) MAKEXC() }   // XC for t=0

    float v0,v1,v2,v3,v4,v5, g0,g1,g2,g3,g4,g5;

    for (int k = 0; k < 32; k++) {
        int tb = k * 8;
        int cb = k & 1, fb = cb ^ 1;
        const float* XFa = xf + (long)((k+1 < 32 ? k+1 : 31)) * 224;  // fill block k+1
        const float* XFb = xf + (long)((k+2 < 32 ? k+2 : 31)) * 224;  // fill block k+2
        STEP(0, L0,L1,L2,L3)
        STEP(1, L4,L5,L6,L0)
        STEP(2, L1,L2,L3,L4)
        STEP(3, L5,L6,L0,L1)
        STEP(4, L2,L3,L4,L5)
        STEP(5, L6,L0,L1,L2)
        STEP(6, L3,L4,L5,L6)
        STEP7
    }
    // ---- h_final
    float* f0p = hfin + (long)(bb + n) * H_;
    *(float4*)(f0p + xo) = make_float4(v0, v1, v2, v3);
    if (!h) *(float2*)(f0p + 8) = make_float2(v4, v5);
    float* f1p = f0p + BH;
    *(float4*)(f1p + xo) = make_float4(g0, g1, g2, g3);
    if (!h) *(float2*)(f1p + 8) = make_float2(g4, g5);
}

extern "C" void kernel_launch(void* const* d_in, const int* in_sizes, int n_in,
                              void* d_out, int out_size, void* d_ws, size_t ws_size,
                              hipStream_t stream) {
    const float* x     = (const float*)d_in[0];
    const float* h0in  = (const float*)d_in[1];
    const float* Wih0  = (const float*)d_in[2];
    const float* Whh0  = (const float*)d_in[3];
    const float* bih0  = (const float*)d_in[4];
    const float* bhh0  = (const float*)d_in[5];
    const float* Wih1  = (const float*)d_in[6];
    const float* Whh1  = (const float*)d_in[7];
    const float* bih1  = (const float*)d_in[8];
    const float* bhh1  = (const float*)d_in[9];
    float* out = (float*)d_out;

    rnn_fused<<<dim3(B_ / 32), dim3(64), 0, stream>>>(
        x, h0in, Wih0, Whh0, bih0, bhh0, Wih1, Whh1, bih1, bhh1,
        out, out + OUT_MAIN);
}

// Round 12
// 137.129 us; speedup vs baseline: 1.2470x; 1.2470x over previous
//
#include <hip/hip_runtime.h>

// Sizes (fixed by the problem)
#define B_ 8192
#define T_ 256
#define I_ 28
#define H_ 10

// d_out layout: [B*T*H] output, then [2*B*H] h_final
#define OUT_MAIN (B_ * T_ * H_)   // 20971520
#define BH (B_ * H_)              // 81920

typedef __bf16 bf16x8 __attribute__((ext_vector_type(8)));
typedef float f32x16 __attribute__((ext_vector_type(16)));
typedef float f32x4  __attribute__((ext_vector_type(4)));
union W4u { unsigned int w[4]; bf16x8 v; };

__device__ __forceinline__ float fast_tanh(float x) {
    float e = __builtin_amdgcn_exp2f(x * 2.885390081777927f);
    return __builtin_fmaf(-2.0f, __builtin_amdgcn_rcpf(e + 1.0f), 1.0f);
}

__device__ __forceinline__ unsigned short f2bf(float f) {  // f32 -> bf16 RNE
    unsigned u = __float_as_uint(f);
    unsigned r = ((u >> 16) & 1) + 0x7fff;
    return (unsigned short)((u + r) >> 16);
}

// pack (f0,f1) -> bf16 pair dh, and residual pair dl (split-bf16: f ~= hi + lo)
__device__ __forceinline__ void cvtpair(float f0, float f1, unsigned& dh, unsigned& dl) {
    asm("v_cvt_pk_bf16_f32 %0, %1, %2" : "=v"(dh) : "v"(f0), "v"(f1));
    float r0 = f0 - __uint_as_float(dh << 16);
    float r1 = f1 - __uint_as_float(dh & 0xffff0000u);
    asm("v_cvt_pk_bf16_f32 %0, %1, %2" : "=v"(dl) : "v"(r0), "v"(r1));
}

// C->B rebuild (validated r7): pads land exactly 0
#define REBUILD(vv0,vv1,vv2,vv3,vv4,vv5, DST) { \
    unsigned t01, t23, t45, w3 = 0; \
    asm("v_cvt_pk_bf16_f32 %0, %1, %2" : "=v"(t01) : "v"(vv0), "v"(vv1)); \
    asm("v_cvt_pk_bf16_f32 %0, %1, %2" : "=v"(t23) : "v"(vv2), "v"(vv3)); \
    asm("v_cvt_pk_bf16_f32 %0, %1, %2" : "=v"(t45) : "v"(vv4), "v"(vv5)); \
    asm volatile("s_nop 1" : "+v"(t01), "+v"(t23), "+v"(t45)); \
    asm("v_permlane32_swap_b32 %0, %1" : "+v"(t01), "+v"(t45)); \
    asm("v_permlane32_swap_b32 %0, %1" : "+v"(t23), "+v"(w3)); \
    W4u nb_; nb_.w[0]=t01; nb_.w[1]=t23; nb_.w[2]=t45; nb_.w[3]=w3; \
    DST = nb_.v; }

// x-prefetch: inline-asm loads (non-remat) + EXACT counted vmcnt.
// r12 post-mortem of r8-r11: per-step issue order is st_t(2) -> WAIT -> L_t(4),
// so ops younger than the needed L_{t-3} at the wait point number
// st_{t-2}2 + L_{t-2}4 + st_{t-1}2 + L_{t-1}4 + st_t2 = 14. The old vmcnt(8)
// over-drained by 6 ops: every step waited for loads only ONE step old (raw
// HBM latency) and for scattered stores from two steps ago. That was the
// ~1000+ cyc/step floor of r8-r11. Exact N=14 never waits on stores and gives
// the needed load 3 full steps of slack.
#define GLD4o(dst, addr, OFF) \
    asm volatile("global_load_dwordx4 %0, %1, off offset:" #OFF : "=v"(dst) : "v"(addr));

#define LOADX(SA, SB, SC, SD, tt) { \
    const float* a0_ = xrow + (long)(tt) * I_ + 8 * h; \
    const float* a1_ = xrow + (long)(tt) * I_ + 20; \
    GLD4o(SA, a0_, 0) \
    GLD4o(SB, a0_, 16) \
    GLD4o(SC, a0_, 64) \
    GLD4o(SD, a1_, 0) }

#define WAITX(SA, SB, SC, SD, N) \
    asm volatile("s_waitcnt vmcnt(" #N ")" : "+v"(SA), "+v"(SB), "+v"(SC), "+v"(SD));

#define GST4(addr, val) \
    asm volatile("global_store_dwordx4 %0, %1, off" :: "v"(addr), "v"(val));
#define GST2a(addr, v0_, v1_) { \
    float2 gw_ = make_float2(v0_, v1_); \
    asm volatile("global_store_dwordx2 %0, %1, off" :: "v"(addr), "v"(gw_)); }

// XC = b0 + Wh*xl + Wl*xh + Wh*xh (6-chain form, r8/r9-validated)
#define MAKEXC(SA, SB, SC, SD) { \
    W4u xhA, xlA, xhB, xlB; \
    cvtpair(SA[0], SA[1], xhA.w[0], xlA.w[0]); \
    cvtpair(SA[2], SA[3], xhA.w[1], xlA.w[1]); \
    cvtpair(SB[0], SB[1], xhA.w[2], xlA.w[2]); \
    cvtpair(SB[2], SB[3], xhA.w[3], xlA.w[3]); \
    cvtpair(SC[0], SC[1], xhB.w[0], xlB.w[0]); \
    cvtpair(SC[2], SC[3], xhB.w[1], xlB.w[1]); \
    cvtpair(SD[0], SD[1], xhB.w[2], xlB.w[2]); \
    cvtpair(SD[2], SD[3], xhB.w[3], xlB.w[3]); \
    f32x16 xc = __builtin_amdgcn_mfma_f32_32x32x16_bf16(Axh0, xlA.v, C0SEED, 0,0,0); \
    xc = __builtin_amdgcn_mfma_f32_32x32x16_bf16(Axh1, xlB.v, xc, 0,0,0); \
    xc = __builtin_amdgcn_mfma_f32_32x32x16_bf16(Axl0, xhA.v, xc, 0,0,0); \
    xc = __builtin_amdgcn_mfma_f32_32x32x16_bf16(Axl1, xhB.v, xc, 0,0,0); \
    xc = __builtin_amdgcn_mfma_f32_32x32x16_bf16(Axh0, xhA.v, xc, 0,0,0); \
    XC = __builtin_amdgcn_mfma_f32_32x32x16_bf16(Axh1, xhB.v, xc, 0,0,0); }

// one recurrent step (r9 structure verbatim, only the wait count changed).
#define STEP(s8, PA,PB,PC,PD, NA,NB,NC,ND) { \
    int t = tb + (s8); \
    f32x16 c0  = __builtin_amdgcn_mfma_f32_32x32x16_bf16(Ahh0, Bh0, XC, 0,0,0); \
    f32x16 c1a = __builtin_amdgcn_mfma_f32_32x32x16_bf16(Ahh1, Bh1, C1SEED, 0,0,0); \
    v0 = fast_tanh(c0[0]); v1 = fast_tanh(c0[1]); v2 = fast_tanh(c0[2]); \
    v3 = fast_tanh(c0[3]); v4 = fast_tanh(c0[4]); v5 = fast_tanh(c0[5]); \
    REBUILD(v0,v1,v2,v3,v4,v5, Bh0) \
    f32x16 c1 = __builtin_amdgcn_mfma_f32_32x32x16_bf16(Aih1, Bh0, c1a, 0,0,0); \
    g0 = fast_tanh(c1[0]); g1 = fast_tanh(c1[1]); g2 = fast_tanh(c1[2]); \
    g3 = fast_tanh(c1[3]); g4 = fast_tanh(c1[4]); g5 = fast_tanh(c1[5]); \
    float* op = orow + t * H_; \
    { f32x4 gv_ = {g0,g1,g2,g3}; GST4(op + xo, gv_) } \
    if (!h) GST2a(op + 8, g4, g5) \
    REBUILD(g0,g1,g2,g3,g4,g5, Bh1) \
    WAITX(NA,NB,NC,ND, 14) \
    MAKEXC(NA,NB,NC,ND) \
    int tl = (t + 4 < T_) ? (t + 4) : (T_ - 1); \
    LOADX(PA,PB,PC,PD, tl) }

__global__ __launch_bounds__(64)
__attribute__((amdgpu_waves_per_eu(1, 1)))
void rnn_fused(const float* __restrict__ x, const float* __restrict__ h0in,
               const float* __restrict__ Wih0, const float* __restrict__ Whh0,
               const float* __restrict__ bih0, const float* __restrict__ bhh0,
               const float* __restrict__ Wih1, const float* __restrict__ Whh1,
               const float* __restrict__ bih1, const float* __restrict__ bhh1,
               float* __restrict__ out, float* __restrict__ hfin,
               float* __restrict__ ws) {
    const int l = threadIdx.x;
    const int n = l & 31, h = l >> 5;
    const int bb = blockIdx.x * 32;
    const int am = n;

    // ---- recurrent A-frags (bf16, zero-padded), pinned vs remat (r5 lesson)
    W4u a0u, aiu, ahu;
#pragma unroll
    for (int jj = 0; jj < 4; jj++) {
        int k0 = 8*h + 2*jj, k1 = k0 + 1;
        bool r0 = (am < H_) && (k0 < H_), r1 = (am < H_) && (k1 < H_);
        unsigned lo, hi;
        lo = r0 ? f2bf(Whh0[am*H_+k0]) : 0u; hi = r1 ? f2bf(Whh0[am*H_+k1]) : 0u;
        a0u.w[jj] = lo | (hi<<16);
        lo = r0 ? f2bf(Wih1[am*H_+k0]) : 0u; hi = r1 ? f2bf(Wih1[am*H_+k1]) : 0u;
        aiu.w[jj] = lo | (hi<<16);
        lo = r0 ? f2bf(Whh1[am*H_+k0]) : 0u; hi = r1 ? f2bf(Whh1[am*H_+k1]) : 0u;
        ahu.w[jj] = lo | (hi<<16);
    }
    bf16x8 Ahh0 = a0u.v, Aih1 = aiu.v, Ahh1 = ahu.v;
    asm volatile("" : "+v"(Ahh0), "+v"(Aih1), "+v"(Ahh1));

    // ---- Wih0 split hi/lo A-frags, 2 K-slices (slice s: k = 16s+8h+2jj)
    W4u xh0u, xh1u, xl0u, xl1u;
#pragma unroll
    for (int s = 0; s < 2; s++) {
#pragma unroll
        for (int jj = 0; jj < 4; jj++) {
            int k0 = 16*s + 8*h + 2*jj, k1 = k0 + 1;
            unsigned short h0b=0, h1b=0, l0b=0, l1b=0;
            if (am < H_ && k0 < I_) {
                float f = Wih0[am*I_+k0];
                h0b = f2bf(f);
                l0b = f2bf(f - __uint_as_float(((unsigned)h0b)<<16));
            }
            if (am < H_ && k1 < I_) {
                float f = Wih0[am*I_+k1];
                h1b = f2bf(f);
                l1b = f2bf(f - __uint_as_float(((unsigned)h1b)<<16));
            }
            unsigned wh = (unsigned)h0b | ((unsigned)h1b<<16);
            unsigned wl = (unsigned)l0b | ((unsigned)l1b<<16);
            if (s==0) { xh0u.w[jj]=wh; xl0u.w[jj]=wl; }
            else      { xh1u.w[jj]=wh; xl1u.w[jj]=wl; }
        }
    }
    bf16x8 Axh0 = xh0u.v, Axh1 = xh1u.v, Axl0 = xl0u.v, Axl1 = xl1u.v;
    asm volatile("" : "+v"(Axh0), "+v"(Axh1), "+v"(Axl0), "+v"(Axl1));

    // ---- persistent bias-seeded C tuples, pinned
    f32x16 C0SEED, C1SEED;
#pragma unroll
    for (int r = 0; r < 16; r++) { C0SEED[r] = 0.f; C1SEED[r] = 0.f; }
#pragma unroll
    for (int r = 0; r < 6; r++) {
        int mm = (r & 3) + 8 * (r >> 2) + 4 * h;
        if (mm < H_) {
            C0SEED[r] = bih0[mm] + bhh0[mm];
            C1SEED[r] = bih1[mm] + bhh1[mm];
        }
    }
    asm volatile("" : "+v"(C0SEED), "+v"(C1SEED));

    // ---- initial B fragments from h0 (zero-padded)
    W4u b0u, b1u;
#pragma unroll
    for (int jj = 0; jj < 4; jj++) {
        int k0 = 8*h + 2*jj, k1 = k0 + 1;
        float f0 = (k0 < H_) ? h0in[(bb + n) * H_ + k0] : 0.f;
        float f1 = (k1 < H_) ? h0in[(bb + n) * H_ + k1] : 0.f;
        b0u.w[jj] = (unsigned)f2bf(f0) | ((unsigned)f2bf(f1) << 16);
        f0 = (k0 < H_) ? h0in[BH + (bb + n) * H_ + k0] : 0.f;
        f1 = (k1 < H_) ? h0in[BH + (bb + n) * H_ + k1] : 0.f;
        b1u.w[jj] = (unsigned)f2bf(f0) | ((unsigned)f2bf(f1) << 16);
    }
    bf16x8 Bh0 = b0u.v, Bh1 = b1u.v;

    const float* xrow = x   + (long)(bb + n) * (T_ * I_);
    float*       orow = out + (long)(bb + n) * (T_ * H_);
    const int xo = h ? 4 : 0;

    // ---- 4-deep prefetch ring: 16 named asm-held f32x4 regs
    f32x4 S00, S01, S02, S03, S10, S11, S12, S13;
    f32x4 S20, S21, S22, S23, S30, S31, S32, S33;
    LOADX(S00,S01,S02,S03, 0)
    LOADX(S10,S11,S12,S13, 1)
    LOADX(S20,S21,S22,S23, 2)
    LOADX(S30,S31,S32,S33, 3)

    f32x16 XC;
    WAITX(S00,S01,S02,S03, 12)   // exact: younger = L_b,L_c,L_d = 12
    MAKEXC(S00,S01,S02,S03)      // XC for t=0

    // prime the VMEM FIFO with 6 dummy stores to scratch so the first loop
    // steps' younger-count floor >= 15 (in-order retirement makes vmcnt(14)
    // under-wait iff younger_actual <= 10; t=0 real younger = 10 without these).
    {
        f32x4 z_ = {0.f, 0.f, 0.f, 0.f};
        float* wp = ws + l * 4;
        GST4(wp, z_) GST4(wp, z_) GST4(wp, z_)
        GST4(wp, z_) GST4(wp, z_) GST4(wp, z_)
    }

    float v0,v1,v2,v3,v4,v5, g0,g1,g2,g3,g4,g5;

    for (int it = 0; it < T_ / 8; it++) {
        int tb = it * 8;
        STEP(0, S00,S01,S02,S03, S10,S11,S12,S13)
        STEP(1, S10,S11,S12,S13, S20,S21,S22,S23)
        STEP(2, S20,S21,S22,S23, S30,S31,S32,S33)
        STEP(3, S30,S31,S32,S33, S00,S01,S02,S03)
        STEP(4, S00,S01,S02,S03, S10,S11,S12,S13)
        STEP(5, S10,S11,S12,S13, S20,S21,S22,S23)
        STEP(6, S20,S21,S22,S23, S30,S31,S32,S33)
        STEP(7, S30,S31,S32,S33, S00,S01,S02,S03)
    }
    // ---- h_final
    float* f0p = hfin + (long)(bb + n) * H_;
    *(float4*)(f0p + xo) = make_float4(v0, v1, v2, v3);
    if (!h) *(float2*)(f0p + 8) = make_float2(v4, v5);
    float* f1p = f0p + BH;
    *(float4*)(f1p + xo) = make_float4(g0, g1, g2, g3);
    if (!h) *(float2*)(f1p + 8) = make_float2(g4, g5);
}

extern "C" void kernel_launch(void* const* d_in, const int* in_sizes, int n_in,
                              void* d_out, int out_size, void* d_ws, size_t ws_size,
                              hipStream_t stream) {
    const float* x     = (const float*)d_in[0];
    const float* h0in  = (const float*)d_in[1];
    const float* Wih0  = (const float*)d_in[2];
    const float* Whh0  = (const float*)d_in[3];
    const float* bih0  = (const float*)d_in[4];
    const float* bhh0  = (const float*)d_in[5];
    const float* Wih1  = (const float*)d_in[6];
    const float* Whh1  = (const float*)d_in[7];
    const float* bih1  = (const float*)d_in[8];
    const float* bhh1  = (const float*)d_in[9];
    float* out = (float*)d_out;

    rnn_fused<<<dim3(B_ / 32), dim3(64), 0, stream>>>(
        x, h0in, Wih0, Whh0, bih0, bhh0, Wih1, Whh1, bih1, bhh1,
        out, out + OUT_MAIN, (float*)d_ws);
}